// Round 2
// baseline (238.951 us; speedup 1.0000x reference)
//
#include <hip/hip_runtime.h>
#include <hip/hip_bf16.h>

// out[b,n,o] = relu( sum_m efm[b,n,m] * z[b,m,o] + bias[o] ),
// z[b,m,o] = sum_d nfm[b,m,d] * W[o,d]      (matmul associativity)
//
// Kernel A: z (bf16, transposed [o][m], padded 64x264) -> d_ws
// Kernel B: streaming GEMM efm @ z with fused bias+relu epilogue.

typedef float f32x4 __attribute__((ext_vector_type(4)));
typedef short s16x8 __attribute__((ext_vector_type(8)));

#define AS1C(p) ((const __attribute__((address_space(1))) unsigned int*)(p))
#define AS3(p)  ((__attribute__((address_space(3))) unsigned int*)(p))

#define Z_STRIDE 264                      // padded m-stride (bf16 elems)
#define Z_ELEMS  (64 * Z_STRIDE)          // 16896 elems = 33792 B per batch
#define Z_CHUNKS (Z_ELEMS * 2 / 16)       // 2112 16-byte chunks

__device__ __forceinline__ unsigned short f2bf(float f) {
    union { float f; unsigned u; } a; a.f = f;
    unsigned u = a.u;
    unsigned rounded = u + 0x7fffu + ((u >> 16) & 1u);   // RNE
    return (unsigned short)(rounded >> 16);
}

__device__ __forceinline__ s16x8 cvt8(f32x4 lo, f32x4 hi) {
    s16x8 r;
    #pragma unroll
    for (int j = 0; j < 4; ++j) {
        __hip_bfloat16 x = __float2bfloat16(lo[j]);
        __hip_bfloat16 y = __float2bfloat16(hi[j]);
        r[j]     = __builtin_bit_cast(short, x);
        r[4 + j] = __builtin_bit_cast(short, y);
    }
    return r;
}

// ---------------- Kernel A: z = bf16(nfm @ W^T), transposed to ws ----------
__global__ __launch_bounds__(256, 4)
void compute_z(const float* __restrict__ nfm, const float* __restrict__ W,
               unsigned short* __restrict__ zws)
{
    __shared__ unsigned short nfm_s[256 * 72];
    __shared__ unsigned short w_s[64 * 72];
    __shared__ unsigned short z_s[Z_ELEMS];

    const int tid   = threadIdx.x;
    const int lane  = tid & 63;
    const int wv    = tid >> 6;          // 0..3
    const int col16 = lane & 15;
    const int kg    = lane >> 4;
    const int kg8   = kg * 8;
    const int b     = blockIdx.x;
    const float* nfm_b = nfm + (size_t)b * (256 * 50);

    {   // zero the padded staging buffers
        unsigned* p = (unsigned*)nfm_s;
        for (int i = tid; i < 256 * 72 / 2; i += 256) p[i] = 0u;
        unsigned* q = (unsigned*)w_s;
        for (int i = tid; i < 64 * 72 / 2; i += 256) q[i] = 0u;
    }
    __syncthreads();

    for (int i = tid; i < 3200; i += 256) {          // 12800 f32
        f32x4 v = *(const f32x4*)(nfm_b + i * 4);
        int e = i * 4;
        #pragma unroll
        for (int j = 0; j < 4; ++j) {
            int r = (e + j) / 50, k = (e + j) % 50;
            nfm_s[r * 72 + k] = f2bf(v[j]);
        }
    }
    for (int i = tid; i < 625; i += 256) {           // 2500 f32
        f32x4 v = *(const f32x4*)(W + i * 4);
        int e = i * 4;
        #pragma unroll
        for (int j = 0; j < 4; ++j) {
            int o = (e + j) / 50, k = (e + j) % 50;
            w_s[o * 72 + k] = f2bf(v[j]);
        }
    }
    __syncthreads();

    s16x8 wf[2][4];
    #pragma unroll
    for (int kk = 0; kk < 2; ++kk)
        #pragma unroll
        for (int ot = 0; ot < 4; ++ot)
            wf[kk][ot] = *(const s16x8*)&w_s[(ot * 16 + col16) * 72 + kk * 32 + kg8];

    #pragma unroll
    for (int mt = 0; mt < 4; ++mt) {                 // wave owns 64 m-rows
        int row = wv * 64 + mt * 16 + col16;
        s16x8 a0 = *(const s16x8*)&nfm_s[row * 72 + kg8];
        s16x8 a1 = *(const s16x8*)&nfm_s[row * 72 + 32 + kg8];
        #pragma unroll
        for (int ot = 0; ot < 4; ++ot) {
            f32x4 acc = {0.f, 0.f, 0.f, 0.f};
            acc = __builtin_amdgcn_mfma_f32_16x16x32_bf16(a0, wf[0][ot], acc, 0, 0, 0);
            acc = __builtin_amdgcn_mfma_f32_16x16x32_bf16(a1, wf[1][ot], acc, 0, 0, 0);
            #pragma unroll
            for (int r = 0; r < 4; ++r) {
                int m = wv * 64 + mt * 16 + kg * 4 + r;
                int o = ot * 16 + col16;
                z_s[o * Z_STRIDE + m] = f2bf(acc[r]);    // transposed
            }
        }
    }
    __syncthreads();

    // coalesced linear copy LDS -> ws (pad bytes carried along, never read)
    uint4* dst = (uint4*)(zws + (size_t)b * Z_ELEMS);
    const uint4* src = (const uint4*)z_s;
    for (int i = tid; i < Z_CHUNKS; i += 256) dst[i] = src[i];
}

// ---------------- Kernel B: out = relu(efm @ z + bias) --------------------
// grid = 1024 (2 blocks/batch, 128 rows each), 256 threads = 4 waves.
__global__ __launch_bounds__(256, 4)
void gemm_out(const float* __restrict__ efm,
              const unsigned short* __restrict__ zws,
              const float* __restrict__ bias,
              float* __restrict__ out)
{
    __shared__ unsigned short z_s[Z_ELEMS];          // 33792 B

    const int tid   = threadIdx.x;
    const int lane  = tid & 63;
    const int wv    = tid >> 6;
    const int col16 = lane & 15;
    const int kg    = lane >> 4;
    const int kg8   = kg * 8;
    const int bid   = blockIdx.x;
    const int b     = bid >> 1;
    const int rt    = bid & 1;

    // async stage z[b] -> LDS, linear dest (pad pre-baked in ws)
    const unsigned short* zb = zws + (size_t)b * Z_ELEMS;
    #pragma unroll
    for (int i = 0; i < 9; ++i) {
        int idx = i * 256 + tid;                     // 16B chunk id
        if (idx < Z_CHUNKS) {                        // wave-uniform guard
            __builtin_amdgcn_global_load_lds(
                AS1C((const char*)zb + (size_t)idx * 16),
                AS3((char*)z_s + (i * 256 + wv * 64) * 16), 16, 0, 0);
        }
    }

    float bia[4];
    #pragma unroll
    for (int ot = 0; ot < 4; ++ot) {
        int c = ot * 16 + col16;
        bia[ot] = (c < 50) ? bias[c] : 0.f;
    }
    __syncthreads();                                 // drains vmcnt too

    const float* efm_b = efm + (size_t)b * (256 * 256);
    float*       out_b = out + (size_t)b * (256 * 50);
    const int r0 = rt * 128 + wv * 32;               // wave's 32 rows

    f32x4 acc[2][4];
    #pragma unroll
    for (int mt = 0; mt < 2; ++mt)
        #pragma unroll
        for (int ot = 0; ot < 4; ++ot)
            acc[mt][ot] = (f32x4){0.f, 0.f, 0.f, 0.f};

    const float* ap0 = efm_b + (r0 + col16) * 256 + kg8;
    const float* ap1 = efm_b + (r0 + 16 + col16) * 256 + kg8;

    f32x4 lo0 = *(const f32x4*)ap0, hi0 = *(const f32x4*)(ap0 + 4);
    f32x4 lo1 = *(const f32x4*)ap1, hi1 = *(const f32x4*)(ap1 + 4);

    #pragma unroll
    for (int ks = 0; ks < 8; ++ks) {
        f32x4 nlo0, nhi0, nlo1, nhi1;
        if (ks < 7) {                                // depth-1 reg prefetch
            const float* p0 = ap0 + (ks + 1) * 32;
            const float* p1 = ap1 + (ks + 1) * 32;
            nlo0 = *(const f32x4*)p0; nhi0 = *(const f32x4*)(p0 + 4);
            nlo1 = *(const f32x4*)p1; nhi1 = *(const f32x4*)(p1 + 4);
        }
        s16x8 bf[4];
        #pragma unroll
        for (int ot = 0; ot < 4; ++ot)
            bf[ot] = *(const s16x8*)&z_s[(ot * 16 + col16) * Z_STRIDE + ks * 32 + kg8];

        s16x8 a0 = cvt8(lo0, hi0);
        s16x8 a1 = cvt8(lo1, hi1);
        #pragma unroll
        for (int ot = 0; ot < 4; ++ot) {
            acc[0][ot] = __builtin_amdgcn_mfma_f32_16x16x32_bf16(a0, bf[ot], acc[0][ot], 0, 0, 0);
            acc[1][ot] = __builtin_amdgcn_mfma_f32_16x16x32_bf16(a1, bf[ot], acc[1][ot], 0, 0, 0);
        }
        lo0 = nlo0; hi0 = nhi0; lo1 = nlo1; hi1 = nhi1;
    }

    #pragma unroll
    for (int mt = 0; mt < 2; ++mt)
        #pragma unroll
        for (int ot = 0; ot < 4; ++ot) {
            int o = ot * 16 + col16;
            if (o < 50) {
                #pragma unroll
                for (int r = 0; r < 4; ++r) {
                    int n = r0 + mt * 16 + kg * 4 + r;
                    out_b[n * 50 + o] = fmaxf(acc[mt][ot][r] + bia[ot], 0.f);
                }
            }
        }
}

// ---------------- fallback: previous monolithic kernel --------------------
__global__ __launch_bounds__(512, 4)
void gconv_fused(const float* __restrict__ nfm, const float* __restrict__ efm,
                 const float* __restrict__ W, const float* __restrict__ bias,
                 float* __restrict__ out)
{
    __shared__ unsigned short nfm_s[256 * 72];
    __shared__ unsigned short w_s[64 * 72];
    __shared__ unsigned short z_s[64 * 264];

    const int tid = threadIdx.x, lane = tid & 63, wv = tid >> 6;
    const int col16 = lane & 15, kg = lane >> 4, kg8 = kg * 8;
    const int b = blockIdx.x;
    const float* nfm_b = nfm + (size_t)b * (256 * 50);
    const float* efm_b = efm + (size_t)b * (256 * 256);
    float*       out_b = out + (size_t)b * (256 * 50);

    {
        unsigned* p = (unsigned*)nfm_s;
        for (int i = tid; i < 256 * 72 / 2; i += 512) p[i] = 0u;
        unsigned* q = (unsigned*)w_s;
        for (int i = tid; i < 64 * 72 / 2; i += 512) q[i] = 0u;
    }
    __syncthreads();
    for (int i = tid; i < 3200; i += 512) {
        f32x4 v = *(const f32x4*)(nfm_b + i * 4);
        int e = i * 4;
        #pragma unroll
        for (int j = 0; j < 4; ++j) {
            int r = (e + j) / 50, k = (e + j) % 50;
            nfm_s[r * 72 + k] = f2bf(v[j]);
        }
    }
    for (int i = tid; i < 625; i += 512) {
        f32x4 v = *(const f32x4*)(W + i * 4);
        int e = i * 4;
        #pragma unroll
        for (int j = 0; j < 4; ++j) {
            int o = (e + j) / 50, k = (e + j) % 50;
            w_s[o * 72 + k] = f2bf(v[j]);
        }
    }
    float bia[4];
    #pragma unroll
    for (int ot = 0; ot < 4; ++ot) {
        int c = ot * 16 + col16;
        bia[ot] = (c < 50) ? bias[c] : 0.f;
    }
    __syncthreads();
    {
        s16x8 wf[2][4];
        #pragma unroll
        for (int kk = 0; kk < 2; ++kk)
            #pragma unroll
            for (int ot = 0; ot < 4; ++ot)
                wf[kk][ot] = *(const s16x8*)&w_s[(ot * 16 + col16) * 72 + kk * 32 + kg8];
        #pragma unroll
        for (int mt = 0; mt < 2; ++mt) {
            int row = wv * 32 + mt * 16 + col16;
            s16x8 a0 = *(const s16x8*)&nfm_s[row * 72 + kg8];
            s16x8 a1 = *(const s16x8*)&nfm_s[row * 72 + 32 + kg8];
            #pragma unroll
            for (int ot = 0; ot < 4; ++ot) {
                f32x4 acc = {0.f, 0.f, 0.f, 0.f};
                acc = __builtin_amdgcn_mfma_f32_16x16x32_bf16(a0, wf[0][ot], acc, 0, 0, 0);
                acc = __builtin_amdgcn_mfma_f32_16x16x32_bf16(a1, wf[1][ot], acc, 0, 0, 0);
                #pragma unroll
                for (int r = 0; r < 4; ++r)
                    z_s[(ot * 16 + col16) * 264 + wv * 32 + mt * 16 + kg * 4 + r] = f2bf(acc[r]);
            }
        }
    }
    __syncthreads();
    f32x4 acc[2][4];
    #pragma unroll
    for (int mt = 0; mt < 2; ++mt)
        #pragma unroll
        for (int ot = 0; ot < 4; ++ot)
            acc[mt][ot] = (f32x4){0.f, 0.f, 0.f, 0.f};
    const int wrow = wv * 32;
    #pragma unroll
    for (int ks = 0; ks < 8; ++ks) {
        s16x8 bf[4];
        #pragma unroll
        for (int ot = 0; ot < 4; ++ot)
            bf[ot] = *(const s16x8*)&z_s[(ot * 16 + col16) * 264 + ks * 32 + kg8];
        #pragma unroll
        for (int mt = 0; mt < 2; ++mt) {
            const float* ap = efm_b + (wrow + mt * 16 + col16) * 256 + ks * 32 + kg8;
            f32x4 lo = *(const f32x4*)ap;
            f32x4 hi = *(const f32x4*)(ap + 4);
            s16x8 af = cvt8(lo, hi);
            #pragma unroll
            for (int ot = 0; ot < 4; ++ot)
                acc[mt][ot] = __builtin_amdgcn_mfma_f32_16x16x32_bf16(af, bf[ot], acc[mt][ot], 0, 0, 0);
        }
    }
    #pragma unroll
    for (int mt = 0; mt < 2; ++mt)
        #pragma unroll
        for (int ot = 0; ot < 4; ++ot) {
            int o = ot * 16 + col16;
            if (o < 50) {
                #pragma unroll
                for (int r = 0; r < 4; ++r) {
                    int n = wrow + mt * 16 + kg * 4 + r;
                    out_b[n * 50 + o] = fmaxf(acc[mt][ot][r] + bia[ot], 0.f);
                }
            }
        }
}

extern "C" void kernel_launch(void* const* d_in, const int* in_sizes, int n_in,
                              void* d_out, int out_size, void* d_ws, size_t ws_size,
                              hipStream_t stream) {
    const float* nfm  = (const float*)d_in[0];   // [512,256,50]
    const float* efm  = (const float*)d_in[1];   // [512,256,256]
    const float* W    = (const float*)d_in[2];   // [50,50]
    const float* bias = (const float*)d_in[3];   // [50]
    float* out = (float*)d_out;                  // [512,256,50]

    const size_t need = (size_t)512 * Z_ELEMS * sizeof(unsigned short);  // ~17.3 MB
    if (ws_size >= need) {
        unsigned short* zws = (unsigned short*)d_ws;
        compute_z<<<dim3(512), dim3(256), 0, stream>>>(nfm, W, zws);
        gemm_out<<<dim3(1024), dim3(256), 0, stream>>>(efm, zws, bias, out);
    } else {
        gconv_fused<<<dim3(512), dim3(512), 0, stream>>>(nfm, efm, W, bias, out);
    }
}

// Round 3
// 227.559 us; speedup vs baseline: 1.0501x; 1.0501x over previous
//
#include <hip/hip_runtime.h>
#include <hip/hip_bf16.h>

// out[b,n,o] = relu( sum_m efm[b,n,m] * z[b,m,o] + bias[o] ),
// z[b,m,o]   = sum_d nfm[b,m,d] * W[o,d]        (matmul associativity)
//
// Single fused kernel: 512 blocks (1/batch) x 512 threads (8 waves).
// LDS: nfm_p [256][64] bf16 swizzled (32KB) + w_s [64][64] bf16 swizzled (8KB)
//    + z_s [64 o][264 m] bf16 (33.8KB)  = 73.8 KB -> 2 blocks/CU.

typedef float f32x4 __attribute__((ext_vector_type(4)));
typedef short s16x8 __attribute__((ext_vector_type(8)));

#define TPB 512

__device__ __forceinline__ unsigned short f2bf(float f) {
    __hip_bfloat16 h = __float2bfloat16(f);           // RNE
    return __builtin_bit_cast(unsigned short, h);
}

__device__ __forceinline__ unsigned bfpair(float a, float b) {
    return (unsigned)f2bf(a) | ((unsigned)f2bf(b) << 16);
}

__device__ __forceinline__ s16x8 cvt8(f32x4 lo, f32x4 hi) {
    s16x8 r;
    #pragma unroll
    for (int j = 0; j < 4; ++j) {
        r[j]     = (short)f2bf(lo[j]);
        r[4 + j] = (short)f2bf(hi[j]);
    }
    return r;
}

// chunk-level XOR swizzle for 64-elem bf16 rows (8 chunks of 8 elems):
// element (row,k) -> row*64 + ((k>>3 ^ (row&7))<<3) + (k&7)
__device__ __forceinline__ int swz(int row, int k) {
    return row * 64 + ((((k >> 3) ^ (row & 7)) << 3) | (k & 7));
}

__global__ __launch_bounds__(TPB, 4)
void gconv_v3(const float* __restrict__ nfm,
              const float* __restrict__ efm,
              const float* __restrict__ W,
              const float* __restrict__ bias,
              float* __restrict__ out)
{
    __shared__ unsigned short nfm_p[256 * 64];
    __shared__ unsigned short w_s[64 * 64];
    __shared__ unsigned short z_s[64 * 264];

    const int tid   = threadIdx.x;
    const int lane  = tid & 63;
    const int wv    = tid >> 6;          // 0..7
    const int col16 = lane & 15;
    const int kg    = lane >> 4;         // 0..3
    const int kg8   = kg * 8;
    const int b     = blockIdx.x;

    const float* nfm_b = nfm + (size_t)b * (256 * 50);
    const float* efm_b = efm + (size_t)b * (256 * 256);
    float*       out_b = out + (size_t)b * (256 * 50);

    // ---- issue first efm K-step loads IMMEDIATELY (fills HBM pipe) ----
    const int r0 = wv * 32;
    const float* ap0 = efm_b + (r0 + col16) * 256 + kg8;
    const float* ap1 = efm_b + (r0 + 16 + col16) * 256 + kg8;
    f32x4 lo0 = *(const f32x4*)ap0, hi0 = *(const f32x4*)(ap0 + 4);
    f32x4 lo1 = *(const f32x4*)ap1, hi1 = *(const f32x4*)(ap1 + 4);

    // ---- zero swizzled staging buffers ----
    {
        unsigned* p = (unsigned*)nfm_p;
        #pragma unroll
        for (int i = 0; i < 16; ++i) p[i * TPB + tid] = 0u;   // 8192 dwords
        unsigned* q = (unsigned*)w_s;
        #pragma unroll
        for (int i = 0; i < 4; ++i) q[i * TPB + tid] = 0u;    // 2048 dwords
    }
    __syncthreads();

    // ---- stage nfm[b] and W as bf16 (swizzled writes) ----
    for (int i = tid; i < 3200; i += TPB) {          // 12800 f32
        f32x4 v = *(const f32x4*)(nfm_b + i * 4);
        int e = i * 4;
        #pragma unroll
        for (int j = 0; j < 4; ++j) {
            int r = (e + j) / 50, k = (e + j) % 50;
            nfm_p[swz(r, k)] = f2bf(v[j]);
        }
    }
    for (int i = tid; i < 625; i += TPB) {           // 2500 f32
        f32x4 v = *(const f32x4*)(W + i * 4);
        int e = i * 4;
        #pragma unroll
        for (int j = 0; j < 4; ++j) {
            int o = (e + j) / 50, k = (e + j) % 50;
            w_s[swz(o, k)] = f2bf(v[j]);
        }
    }

    float bia[4];
    #pragma unroll
    for (int ot = 0; ot < 4; ++ot) {
        int c = ot * 16 + col16;
        bia[ot] = (c < 50) ? bias[c] : 0.f;
    }
    __syncthreads();

    // ---- phase 1: z = nfm @ W^T, stored transposed z_s[o][m] ----
    {
        s16x8 wf[2][4];
        #pragma unroll
        for (int kk = 0; kk < 2; ++kk)
            #pragma unroll
            for (int ot = 0; ot < 4; ++ot) {
                int o = ot * 16 + col16;
                wf[kk][ot] = *(const s16x8*)&w_s[o * 64 + ((((kk << 2) | kg) ^ (o & 7)) << 3)];
            }
        #pragma unroll
        for (int mt = 0; mt < 2; ++mt) {
            int row = wv * 32 + mt * 16 + col16;
            int r7  = row & 7;
            s16x8 a0 = *(const s16x8*)&nfm_p[row * 64 + ((kg ^ r7) << 3)];
            s16x8 a1 = *(const s16x8*)&nfm_p[row * 64 + (((4 | kg) ^ r7) << 3)];
            #pragma unroll
            for (int ot = 0; ot < 4; ++ot) {
                f32x4 acc = {0.f, 0.f, 0.f, 0.f};
                acc = __builtin_amdgcn_mfma_f32_16x16x32_bf16(a0, wf[0][ot], acc, 0, 0, 0);
                acc = __builtin_amdgcn_mfma_f32_16x16x32_bf16(a1, wf[1][ot], acc, 0, 0, 0);
                // D layout: col=lane&15 (=o), row=kg*4+r (=m offset)
                int m = wv * 32 + mt * 16 + kg * 4;
                int o = ot * 16 + col16;
                *(unsigned*)&z_s[o * 264 + m]     = bfpair(acc[0], acc[1]);
                *(unsigned*)&z_s[o * 264 + m + 2] = bfpair(acc[2], acc[3]);
            }
        }
    }
    __syncthreads();

    // ---- phase 2: out = relu(efm @ z + bias), wave owns 32 rows ----
    f32x4 acc[2][4];
    #pragma unroll
    for (int mt = 0; mt < 2; ++mt)
        #pragma unroll
        for (int ot = 0; ot < 4; ++ot)
            acc[mt][ot] = (f32x4){0.f, 0.f, 0.f, 0.f};

    #pragma unroll
    for (int ks = 0; ks < 8; ++ks) {
        f32x4 nlo0, nhi0, nlo1, nhi1;
        if (ks < 7) {                                // depth-1 reg prefetch
            const float* p0 = ap0 + (ks + 1) * 32;
            const float* p1 = ap1 + (ks + 1) * 32;
            nlo0 = *(const f32x4*)p0; nhi0 = *(const f32x4*)(p0 + 4);
            nlo1 = *(const f32x4*)p1; nhi1 = *(const f32x4*)(p1 + 4);
        }
        s16x8 bf[4];
        #pragma unroll
        for (int ot = 0; ot < 4; ++ot)
            bf[ot] = *(const s16x8*)&z_s[(ot * 16 + col16) * 264 + ks * 32 + kg8];

        s16x8 a0 = cvt8(lo0, hi0);
        s16x8 a1 = cvt8(lo1, hi1);
        #pragma unroll
        for (int ot = 0; ot < 4; ++ot) {
            acc[0][ot] = __builtin_amdgcn_mfma_f32_16x16x32_bf16(a0, bf[ot], acc[0][ot], 0, 0, 0);
            acc[1][ot] = __builtin_amdgcn_mfma_f32_16x16x32_bf16(a1, bf[ot], acc[1][ot], 0, 0, 0);
        }
        lo0 = nlo0; hi0 = nhi0; lo1 = nlo1; hi1 = nhi1;
    }

    // ---- epilogue: bias + relu + masked store (o < 50) ----
    #pragma unroll
    for (int mt = 0; mt < 2; ++mt)
        #pragma unroll
        for (int ot = 0; ot < 4; ++ot) {
            int o = ot * 16 + col16;
            if (o < 50) {
                #pragma unroll
                for (int r = 0; r < 4; ++r) {
                    int n = r0 + mt * 16 + kg * 4 + r;
                    out_b[n * 50 + o] = fmaxf(acc[mt][ot][r] + bia[ot], 0.f);
                }
            }
        }
}

extern "C" void kernel_launch(void* const* d_in, const int* in_sizes, int n_in,
                              void* d_out, int out_size, void* d_ws, size_t ws_size,
                              hipStream_t stream) {
    const float* nfm  = (const float*)d_in[0];   // [512,256,50]
    const float* efm  = (const float*)d_in[1];   // [512,256,256]
    const float* W    = (const float*)d_in[2];   // [50,50]
    const float* bias = (const float*)d_in[3];   // [50]
    float* out = (float*)d_out;                  // [512,256,50]

    gconv_v3<<<dim3(512), dim3(TPB), 0, stream>>>(nfm, efm, W, bias, out);
}